// Round 2
// baseline (393.209 us; speedup 1.0000x reference)
//
#include <hip/hip_runtime.h>

// GLIFR RNN (B=64, T=200, IN=512, HID=1024, OUT=512), fp32 in/out, bf16 MFMA.
//
// DELAY=20 decouples the lateral matmul -> 10 chunks of 20 steps. Per chunk:
// one MFMA GEMM (1280x1024x1024) for the lateral synaptic current, then an
// elementwise kernel running the 20-step GLIFR recurrence in registers.
// Input projection and readout are single big GEMMs over all T*B rows.
//
// Workspace (~84 MB):
//   syn   fp32 [T,B,H]  @ 0          (52428800 B)  x_proj, then syn in-place
//   state fp32 4x[B*H]  @ 52428800   (1048576 B)   volt, asc0, asc1, firing
//   F     bf16 [T,B,H]  @ 53477376   (26214400 B)  firing history
//   WinT  bf16 [H,IN]   @ 79691776   (1048576 B)
//   WlatT bf16 [H,H]    @ 80740352   (2097152 B)
//   WoutB bf16 [OUT,H]  @ 82837504   (1048576 B)

typedef float f32x4 __attribute__((ext_vector_type(4)));
typedef __bf16 bf16x8 __attribute__((ext_vector_type(8)));
typedef unsigned short ushortx8 __attribute__((ext_vector_type(8)));
typedef unsigned short ushortx4 __attribute__((ext_vector_type(4)));

__device__ __forceinline__ unsigned short f2b(float f) {
    unsigned int u = __float_as_uint(f);
    unsigned int r = u + 0x7FFFu + ((u >> 16) & 1u);   // RNE
    return (unsigned short)(r >> 16);
}
__device__ __forceinline__ float sigmoidf(float x) {
    return 1.0f / (1.0f + __expf(-x));
}

// ---------------------------------------------------------------------------
// fp32 [R,C] -> bf16 transposed [C,R]
// ---------------------------------------------------------------------------
__global__ __launch_bounds__(256) void transpose_f32_to_bf16(
    const float* __restrict__ in, unsigned short* __restrict__ out,
    int R, int C)
{
    __shared__ unsigned short t[64][65];
    int bx = blockIdx.x * 64, by = blockIdx.y * 64;
    int tx = threadIdx.x & 63, ty = threadIdx.x >> 6;
    for (int r = ty; r < 64; r += 4)
        t[r][tx] = f2b(in[(size_t)(by + r) * C + bx + tx]);
    __syncthreads();
    for (int r = ty; r < 64; r += 4)
        out[(size_t)(bx + r) * R + by + tx] = t[tx][r];
}

// fp32 -> bf16 elementwise (n multiple of 1024)
__global__ __launch_bounds__(256) void convert_f32_to_bf16(
    const float* __restrict__ in, unsigned short* __restrict__ out)
{
    int i = (blockIdx.x * 256 + threadIdx.x) * 4;
    f32x4 v = *(const f32x4*)(in + i);
    ushortx4 o;
    o[0] = f2b(v[0]); o[1] = f2b(v[1]); o[2] = f2b(v[2]); o[3] = f2b(v[3]);
    *(ushortx4*)(out + i) = o;
}

// ---------------------------------------------------------------------------
// NT GEMM: C[m,n] = sum_k A[m,k] * Bt[n,k]   (Bt bf16 row-major, K-contig)
// MODE 0: A fp32 = x [B,T,IN], rows remapped (m=t*64+b -> g=b*200+t),
//         convert to bf16 during staging, zero init, fp32 out. (input proj)
// MODE 1: A bf16, identity rows, fp32 Cin init, fp32 out in-place. (lateral)
// MODE 2: A bf16, identity rows, zero init, +bias, fp32 out remapped to
//         [B,T,OUT]. (readout)
// Block = 256 threads (4 waves in 2x2), wave tile = (BM/2)x(BN/2),
// MFMA 16x16x32 bf16, K-step 32, single-buffered LDS (+8 ushort row pad).
// ---------------------------------------------------------------------------
template<int BM, int BN, int MODE>
__global__ __launch_bounds__(256) void gemm_nt(
    const void* __restrict__ Av,
    const unsigned short* __restrict__ Bt,
    const float* __restrict__ Cin,
    float* __restrict__ outf,
    const float* __restrict__ bias,
    int M, int N, int K)
{
    constexpr int WM = BM / 2, WN = BN / 2;
    constexpr int TM = WM / 16, TN = WN / 16;
    constexpr int LDA = 40;  // 32 + 8 pad (ushorts); 80 B row stride

    __shared__ unsigned short Asm[BM * LDA];
    __shared__ unsigned short Bsm[BN * LDA];

    const int tid  = threadIdx.x;
    const int wave = tid >> 6, lane = tid & 63;
    const int m16  = lane & 15, quad = lane >> 4;
    const int bm0  = blockIdx.y * BM, bn0 = blockIdx.x * BN;
    const int wr   = (wave >> 1) * WM, wc = (wave & 1) * WN;

    f32x4 acc[TM][TN];
#pragma unroll
    for (int i = 0; i < TM; i++)
#pragma unroll
        for (int j = 0; j < TN; j++) {
            if (MODE == 1) {
#pragma unroll
                for (int v = 0; v < 4; v++) {
                    int row = bm0 + wr + i * 16 + quad * 4 + v;
                    int col = bn0 + wc + j * 16 + m16;
                    acc[i][j][v] = Cin[(size_t)row * N + col];
                }
            } else {
                acc[i][j] = (f32x4){0.f, 0.f, 0.f, 0.f};
            }
        }

    for (int k0 = 0; k0 < K; k0 += 32) {
        if (MODE == 0) {
            // A is fp32 x with row remap; convert during staging
            const float* A = (const float*)Av;
            for (int i = tid; i < BM * 8; i += 256) {
                int r = i >> 3, c = (i & 7) * 4;
                int arow = bm0 + r;
                int g = (arow & 63) * 200 + (arow >> 6);
                f32x4 v = *(const f32x4*)(A + (size_t)g * K + k0 + c);
                ushortx4 o;
                o[0] = f2b(v[0]); o[1] = f2b(v[1]);
                o[2] = f2b(v[2]); o[3] = f2b(v[3]);
                *(ushortx4*)(Asm + r * LDA + c) = o;
            }
        } else {
            const unsigned short* A = (const unsigned short*)Av;
            for (int i = tid; i < BM * 4; i += 256) {
                int r = i >> 2, c = (i & 3) * 8;
                *(ushortx8*)(Asm + r * LDA + c) =
                    *(const ushortx8*)(A + (size_t)(bm0 + r) * K + k0 + c);
            }
        }
        for (int i = tid; i < BN * 4; i += 256) {
            int r = i >> 2, c = (i & 3) * 8;
            *(ushortx8*)(Bsm + r * LDA + c) =
                *(const ushortx8*)(Bt + (size_t)(bn0 + r) * K + k0 + c);
        }
        __syncthreads();

        ushortx8 af[TM], bfr[TN];
#pragma unroll
        for (int i = 0; i < TM; i++)
            af[i] = *(const ushortx8*)(Asm + (wr + i * 16 + m16) * LDA + quad * 8);
#pragma unroll
        for (int j = 0; j < TN; j++)
            bfr[j] = *(const ushortx8*)(Bsm + (wc + j * 16 + m16) * LDA + quad * 8);
#pragma unroll
        for (int i = 0; i < TM; i++)
#pragma unroll
            for (int j = 0; j < TN; j++)
                acc[i][j] = __builtin_amdgcn_mfma_f32_16x16x32_bf16(
                    __builtin_bit_cast(bf16x8, af[i]),
                    __builtin_bit_cast(bf16x8, bfr[j]),
                    acc[i][j], 0, 0, 0);
        __syncthreads();
    }

    // epilogue; C/D layout: col = lane&15, row = quad*4 + reg  (m89-verified)
#pragma unroll
    for (int i = 0; i < TM; i++)
#pragma unroll
        for (int j = 0; j < TN; j++) {
            int col = bn0 + wc + j * 16 + m16;
            float bv = (MODE == 2) ? bias[col] : 0.f;
#pragma unroll
            for (int v = 0; v < 4; v++) {
                int row = bm0 + wr + i * 16 + quad * 4 + v;
                if (MODE == 2) {
                    // m = t*64+b  ->  out[(b*200+t)*N + col]
                    size_t o = (size_t)((row & 63) * 200 + (row >> 6)) * N + col;
                    outf[o] = acc[i][j][v] + bv;
                } else {
                    outf[(size_t)row * N + col] = acc[i][j][v];
                }
            }
        }
}

// ---------------------------------------------------------------------------
// GLIFR elementwise recurrence for one chunk of 20 steps.
// One thread per (b,h); state carried in registers, persisted across chunks.
// ---------------------------------------------------------------------------
__global__ __launch_bounds__(256) void chunk_step(
    const float* __restrict__ syn,       // [T,B,H] fp32
    float* __restrict__ state,           // 4 x [B*H]: volt, asc0, asc1, firing
    unsigned short* __restrict__ F,      // [T,B,H] bf16
    const float* __restrict__ thresh,
    const float* __restrict__ t_km,
    const float* __restrict__ t_ak,      // [2,H]
    const float* __restrict__ amp,       // [2,H]
    const float* __restrict__ t_ar,      // [2,H]
    int t0)
{
    const int BH = 64 * 1024;
    int idx = blockIdx.x * 256 + threadIdx.x;   // b*1024 + h
    int h = idx & 1023;

    float th  = thresh[h];
    float sm  = sigmoidf(t_km[h]);             // DT*k_m
    float rm  = 0.1f * sm;                     // R_MEM*DT*k_m
    float om  = 1.0f - sm;
    float sa0 = sigmoidf(t_ak[h]);
    float sa1 = sigmoidf(t_ak[1024 + h]);
    float am0 = amp[h];
    float am1 = amp[1024 + h];
    float r0  = 1.0f - 2.0f * sigmoidf(t_ar[h]);
    float r1  = 1.0f - 2.0f * sigmoidf(t_ar[1024 + h]);

    float volt, a0, a1, fir;
    if (t0 == 0) {
        volt = 0.f; a0 = 0.f; a1 = 0.f; fir = 0.f;
    } else {
        volt = state[idx];
        a0   = state[BH + idx];
        a1   = state[2 * BH + idx];
        fir  = state[3 * BH + idx];
    }

#pragma unroll
    for (int s = 0; s < 20; s++) {
        float sv  = syn[(size_t)(t0 + s) * BH + idx];
        float na0 = (am0 + r0 * a0) * fir * sa0 + (1.f - sa0) * a0;
        float na1 = (am1 + r1 * a1) * fir * sa1 + (1.f - sa1) * a1;
        volt = rm * (sv + na0 + na1) + om * volt;
        fir  = sigmoidf(volt - th);
        F[(size_t)(t0 + s) * BH + idx] = f2b(fir);
        a0 = na0; a1 = na1;
    }
    state[idx]          = volt;
    state[BH + idx]     = a0;
    state[2 * BH + idx] = a1;
    state[3 * BH + idx] = fir;
}

// ---------------------------------------------------------------------------
extern "C" void kernel_launch(void* const* d_in, const int* in_sizes, int n_in,
                              void* d_out, int out_size, void* d_ws, size_t ws_size,
                              hipStream_t stream)
{
    const float* x      = (const float*)d_in[0];  // [64,200,512]
    const float* W_in   = (const float*)d_in[1];  // [512,1024]
    const float* W_lat  = (const float*)d_in[2];  // [1024,1024]
    const float* thresh = (const float*)d_in[3];  // [1,1024]
    const float* t_km   = (const float*)d_in[4];  // [1,1024]
    const float* t_ak   = (const float*)d_in[5];  // [2,1,1024]
    const float* amp    = (const float*)d_in[6];  // [2,1,1024]
    const float* t_ar   = (const float*)d_in[7];  // [2,1,1024]
    const float* W_out  = (const float*)d_in[8];  // [512,1024] (n,k) already!
    const float* b_out  = (const float*)d_in[9];  // [512]
    float* out = (float*)d_out;                   // [64,200,512]

    char* ws = (char*)d_ws;
    float*          syn   = (float*)ws;                     // [T,B,H] fp32
    float*          state = (float*)(ws + 52428800);
    unsigned short* F     = (unsigned short*)(ws + 53477376);
    unsigned short* WinT  = (unsigned short*)(ws + 79691776);
    unsigned short* WlatT = (unsigned short*)(ws + 80740352);
    unsigned short* WoutB = (unsigned short*)(ws + 82837504);

    // Weight prep: transpose+convert so all GEMMs are NT (K-contig bf16).
    transpose_f32_to_bf16<<<dim3(16, 8),  256, 0, stream>>>(W_in,  WinT,  512,  1024);
    transpose_f32_to_bf16<<<dim3(16, 16), 256, 0, stream>>>(W_lat, WlatT, 1024, 1024);
    convert_f32_to_bf16<<<512, 256, 0, stream>>>(W_out, WoutB);  // [512,1024] is (n,k)

    // x_proj (= syn, chunk 0 has no lateral term): [12800,1024] = x @ W_in
    gemm_nt<128, 128, 0><<<dim3(1024 / 128, 12800 / 128), 256, 0, stream>>>(
        x, WinT, nullptr, syn, nullptr, 12800, 1024, 512);

    chunk_step<<<256, 256, 0, stream>>>(syn, state, F, thresh, t_km, t_ak, amp, t_ar, 0);

    const size_t CHUNK = 20 * 64 * 1024;  // elements per chunk of [T,B,H]
    for (int c = 1; c < 10; c++) {
        // syn[c] = x_proj[c] + F[c-1] @ W_lat   (in-place accumulate via Cin)
        gemm_nt<64, 64, 1><<<dim3(1024 / 64, 1280 / 64), 256, 0, stream>>>(
            F + (size_t)(c - 1) * CHUNK, WlatT,
            syn + (size_t)c * CHUNK, syn + (size_t)c * CHUNK,
            nullptr, 1280, 1024, 1024);
        chunk_step<<<256, 256, 0, stream>>>(syn, state, F, thresh, t_km, t_ak, amp, t_ar, c * 20);
    }

    // readout: out[b,t,:] = F[t,b,:] @ W_out^T + b_out  (W_out already [n,k])
    gemm_nt<128, 128, 2><<<dim3(512 / 128, 12800 / 128), 256, 0, stream>>>(
        F, WoutB, nullptr, out, b_out, 12800, 512, 1024);
}

// Round 3
// 316.091 us; speedup vs baseline: 1.2440x; 1.2440x over previous
//
#include <hip/hip_runtime.h>

// GLIFR RNN (B=64, T=200, IN=512, HID=1024, OUT=512), fp32 in/out, bf16 MFMA.
//
// DELAY=20 decouples the lateral matmul -> 10 chunks of 20 steps. Per chunk:
// one MFMA GEMM (1280x1024x1024) for the lateral synaptic current, then an
// elementwise kernel running the 20-step GLIFR recurrence in registers.
// Input projection and readout are single big GEMMs over all T*B rows.
//
// Round 3: m97-style GEMM — global_load_lds width-16 staging with XOR-swizzled
// LDS layout (swizzle applied on the GLOBAL side since global_load_lds forces
// LDS dest = wave-uniform base + lane*16). BK=64. x converted to bf16 once.
//
// Workspace (~84 MB):
//   syn   fp32 [T,B,H]  @ 0          (52428800 B)  x_proj, then syn in-place
//   state fp32 4x[B*H]  @ 52428800   (1048576 B)   volt, asc0, asc1, firing
//   F     bf16 [T,B,H]  @ 53477376   (26214400 B)  firing history
//     xb  bf16 [12800,512] overlays F (dead before first F write)
//   WinT  bf16 [H,IN]   @ 79691776   (1048576 B)
//   WlatT bf16 [H,H]    @ 80740352   (2097152 B)
//   WoutB bf16 [OUT,H]  @ 82837504   (1048576 B)

typedef float f32x4 __attribute__((ext_vector_type(4)));
typedef __bf16 bf16x8 __attribute__((ext_vector_type(8)));
typedef unsigned short ushortx8 __attribute__((ext_vector_type(8)));
typedef unsigned short ushortx4 __attribute__((ext_vector_type(4)));

__device__ __forceinline__ unsigned short f2b(float f) {
    unsigned int u = __float_as_uint(f);
    unsigned int r = u + 0x7FFFu + ((u >> 16) & 1u);   // RNE
    return (unsigned short)(r >> 16);
}
__device__ __forceinline__ float sigmoidf(float x) {
    return 1.0f / (1.0f + __expf(-x));
}

// async global->LDS, 16 B per lane; lptr must be wave-uniform (HW adds lane*16)
__device__ __forceinline__ void gl_lds16(const unsigned short* g, unsigned short* l) {
    __builtin_amdgcn_global_load_lds(
        (const __attribute__((address_space(1))) void*)g,
        (__attribute__((address_space(3))) void*)l, 16, 0, 0);
}

// ---------------------------------------------------------------------------
// fp32 [R,C] -> bf16 transposed [C,R]
// ---------------------------------------------------------------------------
__global__ __launch_bounds__(256) void transpose_f32_to_bf16(
    const float* __restrict__ in, unsigned short* __restrict__ out,
    int R, int C)
{
    __shared__ unsigned short t[64][65];
    int bx = blockIdx.x * 64, by = blockIdx.y * 64;
    int tx = threadIdx.x & 63, ty = threadIdx.x >> 6;
    for (int r = ty; r < 64; r += 4)
        t[r][tx] = f2b(in[(size_t)(by + r) * C + bx + tx]);
    __syncthreads();
    for (int r = ty; r < 64; r += 4)
        out[(size_t)(bx + r) * R + by + tx] = t[tx][r];
}

// fp32 -> bf16 elementwise (n multiple of 1024)
__global__ __launch_bounds__(256) void convert_f32_to_bf16(
    const float* __restrict__ in, unsigned short* __restrict__ out)
{
    int i = (blockIdx.x * 256 + threadIdx.x) * 4;
    f32x4 v = *(const f32x4*)(in + i);
    ushortx4 o;
    o[0] = f2b(v[0]); o[1] = f2b(v[1]); o[2] = f2b(v[2]); o[3] = f2b(v[3]);
    *(ushortx4*)(out + i) = o;
}

// x [B=64,T=200,IN=512] fp32 -> xb [m=t*64+b][512] bf16
__global__ __launch_bounds__(256) void convert_x(
    const float* __restrict__ x, unsigned short* __restrict__ xb)
{
    size_t i8 = (size_t)(blockIdx.x * 256 + threadIdx.x) * 8;   // grid 3200
    int m = (int)(i8 >> 9), k = (int)(i8 & 511);
    int b = m & 63, t = m >> 6;
    const float* src = x + ((size_t)b * 200 + t) * 512 + k;
    f32x4 v0 = *(const f32x4*)src;
    f32x4 v1 = *(const f32x4*)(src + 4);
    ushortx8 o;
    o[0] = f2b(v0[0]); o[1] = f2b(v0[1]); o[2] = f2b(v0[2]); o[3] = f2b(v0[3]);
    o[4] = f2b(v1[0]); o[5] = f2b(v1[1]); o[6] = f2b(v1[2]); o[7] = f2b(v1[3]);
    *(ushortx8*)(xb + i8) = o;
}

// ---------------------------------------------------------------------------
// NT GEMM: C[m,n] = sum_k A[m,k] * Bt[n,k]; A,Bt bf16 row-major K-contig.
// LDS layout (per tile row, 128 B = 8 slots of 16 B): element chunk c of row r
// lives at slot (c ^ (r&7)) -> conflict-free ds_read_b128 fragments with the
// unpadded layout global_load_lds requires.
// MODE 0: zero init, fp32 out identity rows.            (input projection)
// MODE 1: fp32 Cin init, fp32 out in-place.             (lateral chunk)
// MODE 2: zero init, +bias, fp32 out remapped [B,T,OUT] (readout)
// Block = 256 threads, 4 waves 2x2; wave tile (BM/2)x(BN/2); MFMA 16x16x32.
// ---------------------------------------------------------------------------
template<int BM, int BN, int MODE>
__global__ __launch_bounds__(256) void gemm_nt(
    const unsigned short* __restrict__ A,
    const unsigned short* __restrict__ Bt,
    const float* __restrict__ Cin,
    float* __restrict__ outf,
    const float* __restrict__ bias,
    int M, int N, int K)
{
    constexpr int WM = BM / 2, WN = BN / 2;
    constexpr int TM = WM / 16, TN = WN / 16;

    __shared__ unsigned short Asm[BM * 64];
    __shared__ unsigned short Bsm[BN * 64];

    const int tid  = threadIdx.x;
    const int wave = tid >> 6, lane = tid & 63;
    const int m16  = lane & 15, quad = lane >> 4;
    const int bm0  = blockIdx.y * BM, bn0 = blockIdx.x * BN;
    const int wr   = (wave >> 1) * WM, wc = (wave & 1) * WN;
    const int sr   = lane >> 3;        // row within an 8-row staging group
    const int sc   = lane & 7;         // LDS 16B slot within the row

    f32x4 acc[TM][TN];
#pragma unroll
    for (int i = 0; i < TM; i++)
#pragma unroll
        for (int j = 0; j < TN; j++) {
            if (MODE == 1) {
#pragma unroll
                for (int v = 0; v < 4; v++) {
                    int row = bm0 + wr + i * 16 + quad * 4 + v;
                    int col = bn0 + wc + j * 16 + m16;
                    acc[i][j][v] = Cin[(size_t)row * N + col];
                }
            } else {
                acc[i][j] = (f32x4){0.f, 0.f, 0.f, 0.f};
            }
        }

    for (int k0 = 0; k0 < K; k0 += 64) {
        // async staging: each wave-instr fills 8 rows (1024 B) of LDS
#pragma unroll
        for (int g = wave; g < BM / 8; g += 4) {
            int r = g * 8 + sr;
            int c = sc ^ (r & 7);                       // global-side swizzle
            gl_lds16(A + (size_t)(bm0 + r) * K + k0 + c * 8, Asm + g * 512);
        }
#pragma unroll
        for (int g = wave; g < BN / 8; g += 4) {
            int r = g * 8 + sr;
            int c = sc ^ (r & 7);
            gl_lds16(Bt + (size_t)(bn0 + r) * K + k0 + c * 8, Bsm + g * 512);
        }
        __syncthreads();

        ushortx8 af[2][TM], bfr[2][TN];
#pragma unroll
        for (int kh = 0; kh < 2; kh++) {
#pragma unroll
            for (int i = 0; i < TM; i++) {
                int ra = wr + i * 16 + m16;
                af[kh][i] = *(const ushortx8*)(
                    Asm + ra * 64 + (((kh * 4 + quad) ^ (ra & 7)) * 8));
            }
#pragma unroll
            for (int j = 0; j < TN; j++) {
                int rb = wc + j * 16 + m16;
                bfr[kh][j] = *(const ushortx8*)(
                    Bsm + rb * 64 + (((kh * 4 + quad) ^ (rb & 7)) * 8));
            }
        }
#pragma unroll
        for (int i = 0; i < TM; i++)
#pragma unroll
            for (int j = 0; j < TN; j++) {
                acc[i][j] = __builtin_amdgcn_mfma_f32_16x16x32_bf16(
                    __builtin_bit_cast(bf16x8, af[0][i]),
                    __builtin_bit_cast(bf16x8, bfr[0][j]),
                    acc[i][j], 0, 0, 0);
                acc[i][j] = __builtin_amdgcn_mfma_f32_16x16x32_bf16(
                    __builtin_bit_cast(bf16x8, af[1][i]),
                    __builtin_bit_cast(bf16x8, bfr[1][j]),
                    acc[i][j], 0, 0, 0);
            }
        __syncthreads();
    }

    // epilogue; C/D layout: col = lane&15, row = quad*4 + reg  (m89-verified)
#pragma unroll
    for (int i = 0; i < TM; i++)
#pragma unroll
        for (int j = 0; j < TN; j++) {
            int col = bn0 + wc + j * 16 + m16;
            float bv = (MODE == 2) ? bias[col] : 0.f;
#pragma unroll
            for (int v = 0; v < 4; v++) {
                int row = bm0 + wr + i * 16 + quad * 4 + v;
                if (MODE == 2) {
                    // m = t*64+b  ->  out[(b*200+t)*N + col]
                    size_t o = (size_t)((row & 63) * 200 + (row >> 6)) * N + col;
                    outf[o] = acc[i][j][v] + bv;
                } else {
                    outf[(size_t)row * N + col] = acc[i][j][v];
                }
            }
        }
}

// ---------------------------------------------------------------------------
// GLIFR elementwise recurrence for one chunk of 20 steps.
// ---------------------------------------------------------------------------
__global__ __launch_bounds__(256) void chunk_step(
    const float* __restrict__ syn,       // [T,B,H] fp32
    float* __restrict__ state,           // 4 x [B*H]: volt, asc0, asc1, firing
    unsigned short* __restrict__ F,      // [T,B,H] bf16
    const float* __restrict__ thresh,
    const float* __restrict__ t_km,
    const float* __restrict__ t_ak,      // [2,H]
    const float* __restrict__ amp,       // [2,H]
    const float* __restrict__ t_ar,      // [2,H]
    int t0)
{
    const int BH = 64 * 1024;
    int idx = blockIdx.x * 256 + threadIdx.x;   // b*1024 + h
    int h = idx & 1023;

    float th  = thresh[h];
    float sm  = sigmoidf(t_km[h]);             // DT*k_m
    float rm  = 0.1f * sm;                     // R_MEM*DT*k_m
    float om  = 1.0f - sm;
    float sa0 = sigmoidf(t_ak[h]);
    float sa1 = sigmoidf(t_ak[1024 + h]);
    float am0 = amp[h];
    float am1 = amp[1024 + h];
    float r0  = 1.0f - 2.0f * sigmoidf(t_ar[h]);
    float r1  = 1.0f - 2.0f * sigmoidf(t_ar[1024 + h]);

    float volt, a0, a1, fir;
    if (t0 == 0) {
        volt = 0.f; a0 = 0.f; a1 = 0.f; fir = 0.f;
    } else {
        volt = state[idx];
        a0   = state[BH + idx];
        a1   = state[2 * BH + idx];
        fir  = state[3 * BH + idx];
    }

#pragma unroll
    for (int s = 0; s < 20; s++) {
        float sv  = syn[(size_t)(t0 + s) * BH + idx];
        float na0 = (am0 + r0 * a0) * fir * sa0 + (1.f - sa0) * a0;
        float na1 = (am1 + r1 * a1) * fir * sa1 + (1.f - sa1) * a1;
        volt = rm * (sv + na0 + na1) + om * volt;
        fir  = sigmoidf(volt - th);
        F[(size_t)(t0 + s) * BH + idx] = f2b(fir);
        a0 = na0; a1 = na1;
    }
    state[idx]          = volt;
    state[BH + idx]     = a0;
    state[2 * BH + idx] = a1;
    state[3 * BH + idx] = fir;
}

// ---------------------------------------------------------------------------
extern "C" void kernel_launch(void* const* d_in, const int* in_sizes, int n_in,
                              void* d_out, int out_size, void* d_ws, size_t ws_size,
                              hipStream_t stream)
{
    const float* x      = (const float*)d_in[0];  // [64,200,512]
    const float* W_in   = (const float*)d_in[1];  // [512,1024]
    const float* W_lat  = (const float*)d_in[2];  // [1024,1024]
    const float* thresh = (const float*)d_in[3];  // [1,1024]
    const float* t_km   = (const float*)d_in[4];  // [1,1024]
    const float* t_ak   = (const float*)d_in[5];  // [2,1,1024]
    const float* amp    = (const float*)d_in[6];  // [2,1,1024]
    const float* t_ar   = (const float*)d_in[7];  // [2,1,1024]
    const float* W_out  = (const float*)d_in[8];  // [512,1024] (n,k) already!
    const float* b_out  = (const float*)d_in[9];  // [512]
    float* out = (float*)d_out;                   // [64,200,512]

    char* ws = (char*)d_ws;
    float*          syn   = (float*)ws;                     // [T,B,H] fp32
    float*          state = (float*)(ws + 52428800);
    unsigned short* F     = (unsigned short*)(ws + 53477376);
    unsigned short* xb    = F;  // overlay: dead before first F write
    unsigned short* WinT  = (unsigned short*)(ws + 79691776);
    unsigned short* WlatT = (unsigned short*)(ws + 80740352);
    unsigned short* WoutB = (unsigned short*)(ws + 82837504);

    // Prep: transpose/convert weights to bf16 NT layout; x to bf16 m-order.
    transpose_f32_to_bf16<<<dim3(16, 8),  256, 0, stream>>>(W_in,  WinT,  512,  1024);
    transpose_f32_to_bf16<<<dim3(16, 16), 256, 0, stream>>>(W_lat, WlatT, 1024, 1024);
    convert_f32_to_bf16<<<512, 256, 0, stream>>>(W_out, WoutB);  // [512,1024] is (n,k)
    convert_x<<<3200, 256, 0, stream>>>(x, xb);

    // x_proj (= syn, chunk 0 has no lateral term): [12800,1024] = xb @ WinT^T
    gemm_nt<128, 128, 0><<<dim3(1024 / 128, 12800 / 128), 256, 0, stream>>>(
        xb, WinT, nullptr, syn, nullptr, 12800, 1024, 512);

    chunk_step<<<256, 256, 0, stream>>>(syn, state, F, thresh, t_km, t_ak, amp, t_ar, 0);

    const size_t CHUNK = 20 * 64 * 1024;  // elements per chunk of [T,B,H]
    for (int c = 1; c < 10; c++) {
        // syn[c] = x_proj[c] + F[c-1] @ W_lat   (in-place accumulate via Cin)
        gemm_nt<64, 64, 1><<<dim3(1024 / 64, 1280 / 64), 256, 0, stream>>>(
            F + (size_t)(c - 1) * CHUNK, WlatT,
            syn + (size_t)c * CHUNK, syn + (size_t)c * CHUNK,
            nullptr, 1280, 1024, 1024);
        chunk_step<<<256, 256, 0, stream>>>(syn, state, F, thresh, t_km, t_ak, amp, t_ar, c * 20);
    }

    // readout: out[b,t,:] = F[t,b,:] @ W_out^T + b_out  (W_out already [n,k])
    gemm_nt<128, 128, 2><<<dim3(512 / 128, 12800 / 128), 256, 0, stream>>>(
        F, WoutB, nullptr, out, b_out, 12800, 512, 1024);
}